// Round 20
// baseline (527.142 us; speedup 1.0000x reference)
//
#include <hip/hip_runtime.h>
#include <hip/hip_bf16.h>
#include <math.h>

typedef __attribute__((ext_vector_type(8))) short short8;
typedef __attribute__((ext_vector_type(4))) short short4v;
typedef __attribute__((ext_vector_type(4))) float float4v;
typedef __attribute__((ext_vector_type(2))) unsigned int uint2v;

#define GLD_LDS(g, l) __builtin_amdgcn_global_load_lds( \
    (const __attribute__((address_space(1))) void*)(g), \
    (__attribute__((address_space(3))) void*)(l), 16, 0, 0)

__device__ __forceinline__ short f2bf(float x) {
  __hip_bfloat16 h = __float2bfloat16(x);
  return __builtin_bit_cast(short, h);
}

// raw v_exp_f32 (2^x) -- no OCML fixup (inputs bounded in [-64, 0])
__device__ __forceinline__ float fexp2(float x) {
  return __builtin_amdgcn_exp2f(x);
}

// ---------------- casts fp32 -> bf16 (merged launches) ----------------
__global__ __launch_bounds__(256) void cast3(
    const float4v* __restrict__ in0, const float4v* __restrict__ in1,
    const float4v* __restrict__ in2,
    short4v* __restrict__ o0, short4v* __restrict__ o1, short4v* __restrict__ o2,
    int n4)
{
  const float4v* in = blockIdx.y == 0 ? in0 : blockIdx.y == 1 ? in1 : in2;
  short4v* out = blockIdx.y == 0 ? o0 : blockIdx.y == 1 ? o1 : o2;
  int i = blockIdx.x * 256 + threadIdx.x;
  if (i < n4) {
    float4v v = in[i];
    short4v o;
    o[0] = f2bf(v[0]); o[1] = f2bf(v[1]); o[2] = f2bf(v[2]); o[3] = f2bf(v[3]);
    out[i] = o;
  }
}

__global__ __launch_bounds__(256) void cast4(
    const float4v* __restrict__ in0, const float4v* __restrict__ in1,
    const float4v* __restrict__ in2, const float4v* __restrict__ in3,
    short4v* __restrict__ o0, short4v* __restrict__ o1,
    short4v* __restrict__ o2, short4v* __restrict__ o3,
    int n4)
{
  const float4v* in = blockIdx.y == 0 ? in0 : blockIdx.y == 1 ? in1
                    : blockIdx.y == 2 ? in2 : in3;
  short4v* out = blockIdx.y == 0 ? o0 : blockIdx.y == 1 ? o1
               : blockIdx.y == 2 ? o2 : o3;
  int i = blockIdx.x * 256 + threadIdx.x;
  if (i < n4) {
    float4v v = in[i];
    short4v o;
    o[0] = f2bf(v[0]); o[1] = f2bf(v[1]); o[2] = f2bf(v[2]); o[3] = f2bf(v[3]);
    out[i] = o;
  }
}

// ---------------- bf16 GEMM, B^T layout, 2-phase double-buffered ----------
// MODE 0: C bf16 [M][N] + bias[n]; blockIdx.z selects (A,B,bias,C) pair.
// MODE 1: C bf16 scattered to VT layout, bias[m]
// MODE 2: C f32 [M][N] + bias[n]
template<int MODE>
__global__ __launch_bounds__(256) void gemm_bt(
    const short* __restrict__ A0, const short* __restrict__ B0,
    const float* __restrict__ bias0, void* __restrict__ Cv0,
    const short* __restrict__ A1, const short* __restrict__ B1,
    const float* __restrict__ bias1, void* __restrict__ Cv1,
    int M, int N, int K)
{
  const short* A = blockIdx.z ? A1 : A0;
  const short* B = blockIdx.z ? B1 : B0;
  const float* bias = blockIdx.z ? bias1 : bias0;
  void* Cv = blockIdx.z ? Cv1 : Cv0;

  __shared__ short As[2][128 * 64];
  __shared__ short Bs[2][128 * 64];
  const int tid = threadIdx.x;
  const int w = tid >> 6, lane = tid & 63;
  const int g = lane >> 4, cc = lane & 15;
  const int m0 = blockIdx.x * 128, n0 = blockIdx.y * 128;
  const int wr = (w >> 1) * 64, wc = (w & 1) * 64;

  float4v acc[4][4];
#pragma unroll
  for (int mi = 0; mi < 4; ++mi)
#pragma unroll
    for (int ni = 0; ni < 4; ++ni)
      acc[mi][ni] = (float4v){0.f, 0.f, 0.f, 0.f};

  const int cbase0 = w * 64;
  const int row_l[4] = {(cbase0 + lane) >> 3, (256 + cbase0 + lane) >> 3,
                        (512 + cbase0 + lane) >> 3, (768 + cbase0 + lane) >> 3};
  const int col_l = (lane & 7) * 8;

  auto stage = [&](int buf, int k0) {
#pragma unroll
    for (int i = 0; i < 4; ++i) {
      int cbase = i * 256 + cbase0;
      GLD_LDS(A + (long)(m0 + row_l[i]) * K + k0 + col_l, &As[buf][cbase * 8]);
      GLD_LDS(B + (long)(n0 + row_l[i]) * K + k0 + col_l, &Bs[buf][cbase * 8]);
    }
  };
  auto compute = [&](int buf) {
#pragma unroll
    for (int ks = 0; ks < 2; ++ks) {
      short8 af[4], bfr[4];
#pragma unroll
      for (int mi = 0; mi < 4; ++mi)
        af[mi] = *(const short8*)&As[buf][(wr + mi * 16 + cc) * 64 + ks * 32 + g * 8];
#pragma unroll
      for (int ni = 0; ni < 4; ++ni)
        bfr[ni] = *(const short8*)&Bs[buf][(wc + ni * 16 + cc) * 64 + ks * 32 + g * 8];
#pragma unroll
      for (int mi = 0; mi < 4; ++mi)
#pragma unroll
        for (int ni = 0; ni < 4; ++ni)
          acc[mi][ni] = __builtin_amdgcn_mfma_f32_16x16x32_bf16(
              af[mi], bfr[ni], acc[mi][ni], 0, 0, 0);
    }
  };

  stage(0, 0);
  __syncthreads();
#pragma unroll 1
  for (int k0 = 0; k0 < K; k0 += 128) {
    stage(1, k0 + 64);
    compute(0);
    __syncthreads();
    if (k0 + 128 < K) stage(0, k0 + 128);
    compute(1);
    __syncthreads();
  }

#pragma unroll
  for (int mi = 0; mi < 4; ++mi) {
#pragma unroll
    for (int ni = 0; ni < 4; ++ni) {
      int mb = m0 + wr + mi * 16 + g * 4;
      int nn = n0 + wc + ni * 16 + cc;
      float4v v = acc[mi][ni];
      if constexpr (MODE == 0) {
        float bb = bias[nn];
        __hip_bfloat16* C = (__hip_bfloat16*)Cv;
#pragma unroll
        for (int r = 0; r < 4; ++r)
          C[(long)(mb + r) * N + nn] = __float2bfloat16(v[r] + bb);
      } else if constexpr (MODE == 1) {
        __hip_bfloat16* C = (__hip_bfloat16*)Cv;
        long base = (long)(nn >> 11) * 2097152 + (nn & 2047);
#pragma unroll
        for (int r = 0; r < 4; ++r)
          C[(long)(mb + r) * 2048 + base] = __float2bfloat16(v[r] + bias[mb + r]);
      } else {
        float bb = bias[nn];
        float* C = (float*)Cv;
#pragma unroll
        for (int r = 0; r < 4; ++r)
          C[(long)(mb + r) * N + nn] = v[r] + bb;
      }
    }
  }
}

// ---------------- fused attention (cross-iteration PV pipeline) -----------
// Pass 2 restructured: iteration i computes QK^T(i), writes P(i) into LDS
// buffer i&1 (cols 0 / 72 of the same [32][152] tile -- zero extra LDS),
// stores P(i) to global, and runs PV for iteration i-1 from the OTHER
// buffer, whose writes completed a full iteration ago. Breaks the
// exp->LDSwrite->LDSread->MFMA same-iteration dependency (the last
// untested structural mechanism). Pass 1 keeps the R16 2-tile ILP form.
__global__ __launch_bounds__(256) void attn_fwd(
    const short* __restrict__ Qb, const short* __restrict__ Kb,
    const short* __restrict__ VTb, float* __restrict__ attn_out,
    __hip_bfloat16* __restrict__ Wout)
{
  __shared__ short plds[4][32][152];  // per-wave: buffer0 cols [0,64), buffer1 at [72,136)
  const int S = 2048, D = 1024;
  const int bid = blockIdx.x;
  const int x = bid >> 7, r = bid & 127;
  const int bh = x * 8 + (r & 7), qi = r >> 3;
  const int b = bh >> 4, h = bh & 15;
  const int tid = threadIdx.x, w = tid >> 6, lane = tid & 63;
  const int g = lane >> 4, cc = lane & 15;
  const int q0 = qi * 128 + w * 32;

  const short* Qp = Qb + (long)b * S * D + h * 64;
  const short* Kp = Kb + (long)b * S * D + h * 64;
  const short* Vt = VTb + (long)bh * 64 * S;

  short8 qf[2][2];
#pragma unroll
  for (int mi = 0; mi < 2; ++mi)
#pragma unroll
    for (int ks = 0; ks < 2; ++ks)
      qf[mi][ks] = *(const short8*)(Qp + (long)(q0 + mi * 16 + cc) * D + ks * 32 + g * 8);

  float l[2] = {0.f, 0.f};
  const float C2 = 0.18033688011112042f;  // 0.125 * log2(e)

  // ---- pass 1: denominators, 2 tiles/iter (R16 form) ----
#pragma unroll 1
  for (int kt = 0; kt < S; kt += 128) {
    short8 kfA[2][4], kfB[2][4];
#pragma unroll
    for (int ks = 0; ks < 2; ++ks)
#pragma unroll
      for (int ni = 0; ni < 4; ++ni) {
        kfA[ks][ni] = *(const short8*)(Kp + (long)(kt + ni * 16 + cc) * D + ks * 32 + g * 8);
        kfB[ks][ni] = *(const short8*)(Kp + (long)(kt + 64 + ni * 16 + cc) * D + ks * 32 + g * 8);
      }
    float4v eA[2][4], eB[2][4];
#pragma unroll
    for (int mi = 0; mi < 2; ++mi)
#pragma unroll
      for (int ni = 0; ni < 4; ++ni) {
        eA[mi][ni] = (float4v){0.f, 0.f, 0.f, 0.f};
        eB[mi][ni] = (float4v){0.f, 0.f, 0.f, 0.f};
      }
#pragma unroll
    for (int ks = 0; ks < 2; ++ks)
#pragma unroll
      for (int mi = 0; mi < 2; ++mi)
#pragma unroll
        for (int ni = 0; ni < 4; ++ni) {
          eA[mi][ni] = __builtin_amdgcn_mfma_f32_16x16x32_bf16(
              kfA[ks][ni], qf[mi][ks], eA[mi][ni], 0, 0, 0);
          eB[mi][ni] = __builtin_amdgcn_mfma_f32_16x16x32_bf16(
              kfB[ks][ni], qf[mi][ks], eB[mi][ni], 0, 0, 0);
        }
#pragma unroll
    for (int mi = 0; mi < 2; ++mi)
#pragma unroll
      for (int ni = 0; ni < 4; ++ni)
#pragma unroll
        for (int r2 = 0; r2 < 4; ++r2) {
          l[mi] += fexp2(eA[mi][ni][r2] * C2);
          l[mi] += fexp2(eB[mi][ni][r2] * C2);
        }
  }
  float lrl[2];
#pragma unroll
  for (int mi = 0; mi < 2; ++mi) {
    float s = l[mi];
    s += __shfl_xor(s, 16);
    s += __shfl_xor(s, 32);
    lrl[mi] = -__log2f(s);
  }

  // ---- pass 2: 1 tile/iter, PV deferred one iteration (double-buffer) ----
  float4v Wacc[2][4];
#pragma unroll
  for (int mi = 0; mi < 2; ++mi)
#pragma unroll
    for (int ni = 0; ni < 4; ++ni) Wacc[mi][ni] = (float4v){0.f, 0.f, 0.f, 0.f};

  float* Arow = attn_out + (long)bh * S * S;
#pragma unroll 2
  for (int it = 0; it < 33; ++it) {
    const int kt = it * 64;
    const int cur = (it & 1) * 72;    // this iteration's P buffer column base
    const int prv = ((it ^ 1) & 1) * 72;

    if (it < 32) {
      // QK^T(it)
      short8 kf[2][4];
#pragma unroll
      for (int ks = 0; ks < 2; ++ks)
#pragma unroll
        for (int ni = 0; ni < 4; ++ni)
          kf[ks][ni] = *(const short8*)(Kp + (long)(kt + ni * 16 + cc) * D + ks * 32 + g * 8);
      float4v e[2][4];
#pragma unroll
      for (int mi = 0; mi < 2; ++mi)
#pragma unroll
        for (int ni = 0; ni < 4; ++ni) e[mi][ni] = (float4v){0.f, 0.f, 0.f, 0.f};
#pragma unroll
      for (int ks = 0; ks < 2; ++ks)
#pragma unroll
        for (int mi = 0; mi < 2; ++mi)
#pragma unroll
          for (int ni = 0; ni < 4; ++ni)
            e[mi][ni] = __builtin_amdgcn_mfma_f32_16x16x32_bf16(
                kf[ks][ni], qf[mi][ks], e[mi][ni], 0, 0, 0);
      // softmax finish -> bf16 P into buffer cur
#pragma unroll
      for (int mi = 0; mi < 2; ++mi) {
#pragma unroll
        for (int ni = 0; ni < 4; ++ni) {
          short4v pb;
#pragma unroll
          for (int r2 = 0; r2 < 4; ++r2)
            pb[r2] = f2bf(fexp2(__builtin_fmaf(e[mi][ni][r2], C2, lrl[mi])));
          *(short4v*)&plds[w][mi * 16 + cc][cur + ni * 16 + g * 4] = pb;
        }
      }
      // contiguous P stores from buffer cur (exact <<16 expand)
#pragma unroll
      for (int j = 0; j < 8; ++j) {
        uint2v u = *(const uint2v*)&plds[w][j * 4 + g][cur + cc * 4];
        float4v pv4;
        pv4[0] = __builtin_bit_cast(float, u[0] << 16);
        pv4[1] = __builtin_bit_cast(float, u[0] & 0xffff0000u);
        pv4[2] = __builtin_bit_cast(float, u[1] << 16);
        pv4[3] = __builtin_bit_cast(float, u[1] & 0xffff0000u);
        __builtin_nontemporal_store(
            pv4, (float4v*)(Arow + (long)(q0 + j * 4 + g) * S + kt + cc * 4));
      }
    }

    if (it > 0) {
      // PV for iteration it-1 from buffer prv (writes completed last iter)
      const int ktp = (it - 1) * 64;
#pragma unroll
      for (int ks = 0; ks < 2; ++ks) {
        short8 pa[2], vf[4];
#pragma unroll
        for (int mi = 0; mi < 2; ++mi)
          pa[mi] = *(const short8*)&plds[w][mi * 16 + cc][prv + ks * 32 + g * 8];
#pragma unroll
        for (int ni = 0; ni < 4; ++ni)
          vf[ni] = *(const short8*)(Vt + (long)(ni * 16 + cc) * S + ktp + ks * 32 + g * 8);
#pragma unroll
        for (int mi = 0; mi < 2; ++mi)
#pragma unroll
          for (int ni = 0; ni < 4; ++ni)
            Wacc[mi][ni] = __builtin_amdgcn_mfma_f32_16x16x32_bf16(
                pa[mi], vf[ni], Wacc[mi][ni], 0, 0, 0);
      }
    }
  }

#pragma unroll
  for (int mi = 0; mi < 2; ++mi)
#pragma unroll
    for (int ni = 0; ni < 4; ++ni)
#pragma unroll
      for (int r2 = 0; r2 < 4; ++r2)
        Wout[(long)(b * S + q0 + mi * 16 + g * 4 + r2) * D + h * 64 + ni * 16 + cc] =
            __float2bfloat16(Wacc[mi][ni][r2]);
}

extern "C" void kernel_launch(void* const* d_in, const int* in_sizes, int n_in,
                              void* d_out, int out_size, void* d_ws, size_t ws_size,
                              hipStream_t stream) {
  const float* query = (const float*)d_in[0];
  const float* key   = (const float*)d_in[1];
  const float* value = (const float*)d_in[2];
  const float* wq_w  = (const float*)d_in[3];
  const float* wq_b  = (const float*)d_in[4];
  const float* wk_w  = (const float*)d_in[5];
  const float* wk_b  = (const float*)d_in[6];
  const float* wv_w  = (const float*)d_in[7];
  const float* wv_b  = (const float*)d_in[8];
  const float* fc_w  = (const float*)d_in[9];
  const float* fc_b  = (const float*)d_in[10];

  char* ws = (char*)d_ws;
  short* Qb  = (short*)(ws);                   // 16 MB  [B,S,D] bf16
  short* Kb  = (short*)(ws + 16777216);        // 16 MB
  short* VT  = (short*)(ws + 33554432);        // 16 MB  [B,H,64,S] bf16
  short* Wq  = (short*)(ws + 50331648);        // 2 MB each
  short* Wk  = (short*)(ws + 52428800);
  short* Wv  = (short*)(ws + 54525952);
  short* Wfc = (short*)(ws + 56623104);
  short* Xq  = (short*)(ws + 58720256);        // 16 MB each
  short* Xk  = (short*)(ws + 75497472);
  short* Xv  = (short*)(ws + 92274688);
  short* Wgt = Xq;  // weighted reuses Xq after projections

  float* out0 = (float*)d_out;                 // [B,S,D] fp32
  float* attn_out = out0 + 8388608;            // [B,H,S,S] fp32

  // casts (2 launches)
  cast3<<<dim3(8192, 3), 256, 0, stream>>>(
      (const float4v*)query, (const float4v*)key, (const float4v*)value,
      (short4v*)Xq, (short4v*)Xk, (short4v*)Xv, 2097152);
  cast4<<<dim3(1024, 4), 256, 0, stream>>>(
      (const float4v*)wq_w, (const float4v*)wk_w, (const float4v*)wv_w,
      (const float4v*)fc_w,
      (short4v*)Wq, (short4v*)Wk, (short4v*)Wv, (short4v*)Wfc, 262144);

  // Q and K projections merged into one dispatch (blockIdx.z selects)
  gemm_bt<0><<<dim3(64, 8, 2), 256, 0, stream>>>(
      Xq, Wq, wq_b, Qb, Xk, Wk, wk_b, Kb, 8192, 1024, 1024);
  // V projection with swapped operands -> writes V^T layout
  gemm_bt<1><<<dim3(8, 64), 256, 0, stream>>>(
      Wv, Xv, wv_b, VT, Wv, Xv, wv_b, VT, 1024, 8192, 1024);

  // attention (writes attention fp32 + weighted bf16)
  attn_fwd<<<dim3(1024), 256, 0, stream>>>(Qb, Kb, VT, attn_out,
                                           (__hip_bfloat16*)Wgt);

  // output projection
  gemm_bt<2><<<dim3(64, 8), 256, 0, stream>>>(
      Wgt, Wfc, fc_b, out0, Wgt, Wfc, fc_b, out0, 8192, 1024, 1024);
}

// Round 21
// 517.142 us; speedup vs baseline: 1.0193x; 1.0193x over previous
//
#include <hip/hip_runtime.h>
#include <hip/hip_bf16.h>
#include <math.h>

typedef __attribute__((ext_vector_type(8))) short short8;
typedef __attribute__((ext_vector_type(4))) short short4v;
typedef __attribute__((ext_vector_type(4))) float float4v;
typedef __attribute__((ext_vector_type(2))) unsigned int uint2v;

#define GLD_LDS(g, l) __builtin_amdgcn_global_load_lds( \
    (const __attribute__((address_space(1))) void*)(g), \
    (__attribute__((address_space(3))) void*)(l), 16, 0, 0)

__device__ __forceinline__ short f2bf(float x) {
  __hip_bfloat16 h = __float2bfloat16(x);
  return __builtin_bit_cast(short, h);
}

// raw v_exp_f32 (2^x) -- no OCML fixup (inputs bounded in [-64, 0])
__device__ __forceinline__ float fexp2(float x) {
  return __builtin_amdgcn_exp2f(x);
}

// ---------------- casts fp32 -> bf16 (merged launches) ----------------
__global__ __launch_bounds__(256) void cast3(
    const float4v* __restrict__ in0, const float4v* __restrict__ in1,
    const float4v* __restrict__ in2,
    short4v* __restrict__ o0, short4v* __restrict__ o1, short4v* __restrict__ o2,
    int n4)
{
  const float4v* in = blockIdx.y == 0 ? in0 : blockIdx.y == 1 ? in1 : in2;
  short4v* out = blockIdx.y == 0 ? o0 : blockIdx.y == 1 ? o1 : o2;
  int i = blockIdx.x * 256 + threadIdx.x;
  if (i < n4) {
    float4v v = in[i];
    short4v o;
    o[0] = f2bf(v[0]); o[1] = f2bf(v[1]); o[2] = f2bf(v[2]); o[3] = f2bf(v[3]);
    out[i] = o;
  }
}

__global__ __launch_bounds__(256) void cast4(
    const float4v* __restrict__ in0, const float4v* __restrict__ in1,
    const float4v* __restrict__ in2, const float4v* __restrict__ in3,
    short4v* __restrict__ o0, short4v* __restrict__ o1,
    short4v* __restrict__ o2, short4v* __restrict__ o3,
    int n4)
{
  const float4v* in = blockIdx.y == 0 ? in0 : blockIdx.y == 1 ? in1
                    : blockIdx.y == 2 ? in2 : in3;
  short4v* out = blockIdx.y == 0 ? o0 : blockIdx.y == 1 ? o1
               : blockIdx.y == 2 ? o2 : o3;
  int i = blockIdx.x * 256 + threadIdx.x;
  if (i < n4) {
    float4v v = in[i];
    short4v o;
    o[0] = f2bf(v[0]); o[1] = f2bf(v[1]); o[2] = f2bf(v[2]); o[3] = f2bf(v[3]);
    out[i] = o;
  }
}

// ---------------- bf16 GEMM, B^T layout, 2-phase double-buffered ----------
// MODE 0: C bf16 [M][N] + bias[n]; blockIdx.z selects (A,B,bias,C) pair
//         (merges the Q and K projections into one dispatch).
// MODE 1: C bf16 scattered to VT layout, bias[m]
// MODE 2: C f32 [M][N] + bias[n]
template<int MODE>
__global__ __launch_bounds__(256) void gemm_bt(
    const short* __restrict__ A0, const short* __restrict__ B0,
    const float* __restrict__ bias0, void* __restrict__ Cv0,
    const short* __restrict__ A1, const short* __restrict__ B1,
    const float* __restrict__ bias1, void* __restrict__ Cv1,
    int M, int N, int K)
{
  const short* A = blockIdx.z ? A1 : A0;
  const short* B = blockIdx.z ? B1 : B0;
  const float* bias = blockIdx.z ? bias1 : bias0;
  void* Cv = blockIdx.z ? Cv1 : Cv0;

  __shared__ short As[2][128 * 64];
  __shared__ short Bs[2][128 * 64];
  const int tid = threadIdx.x;
  const int w = tid >> 6, lane = tid & 63;
  const int g = lane >> 4, cc = lane & 15;
  const int m0 = blockIdx.x * 128, n0 = blockIdx.y * 128;
  const int wr = (w >> 1) * 64, wc = (w & 1) * 64;

  float4v acc[4][4];
#pragma unroll
  for (int mi = 0; mi < 4; ++mi)
#pragma unroll
    for (int ni = 0; ni < 4; ++ni)
      acc[mi][ni] = (float4v){0.f, 0.f, 0.f, 0.f};

  const int cbase0 = w * 64;
  const int row_l[4] = {(cbase0 + lane) >> 3, (256 + cbase0 + lane) >> 3,
                        (512 + cbase0 + lane) >> 3, (768 + cbase0 + lane) >> 3};
  const int col_l = (lane & 7) * 8;

  auto stage = [&](int buf, int k0) {
#pragma unroll
    for (int i = 0; i < 4; ++i) {
      int cbase = i * 256 + cbase0;
      GLD_LDS(A + (long)(m0 + row_l[i]) * K + k0 + col_l, &As[buf][cbase * 8]);
      GLD_LDS(B + (long)(n0 + row_l[i]) * K + k0 + col_l, &Bs[buf][cbase * 8]);
    }
  };
  auto compute = [&](int buf) {
#pragma unroll
    for (int ks = 0; ks < 2; ++ks) {
      short8 af[4], bfr[4];
#pragma unroll
      for (int mi = 0; mi < 4; ++mi)
        af[mi] = *(const short8*)&As[buf][(wr + mi * 16 + cc) * 64 + ks * 32 + g * 8];
#pragma unroll
      for (int ni = 0; ni < 4; ++ni)
        bfr[ni] = *(const short8*)&Bs[buf][(wc + ni * 16 + cc) * 64 + ks * 32 + g * 8];
#pragma unroll
      for (int mi = 0; mi < 4; ++mi)
#pragma unroll
        for (int ni = 0; ni < 4; ++ni)
          acc[mi][ni] = __builtin_amdgcn_mfma_f32_16x16x32_bf16(
              af[mi], bfr[ni], acc[mi][ni], 0, 0, 0);
    }
  };

  stage(0, 0);
  __syncthreads();
#pragma unroll 1
  for (int k0 = 0; k0 < K; k0 += 128) {
    stage(1, k0 + 64);
    compute(0);
    __syncthreads();
    if (k0 + 128 < K) stage(0, k0 + 128);
    compute(1);
    __syncthreads();
  }

#pragma unroll
  for (int mi = 0; mi < 4; ++mi) {
#pragma unroll
    for (int ni = 0; ni < 4; ++ni) {
      int mb = m0 + wr + mi * 16 + g * 4;
      int nn = n0 + wc + ni * 16 + cc;
      float4v v = acc[mi][ni];
      if constexpr (MODE == 0) {
        float bb = bias[nn];
        __hip_bfloat16* C = (__hip_bfloat16*)Cv;
#pragma unroll
        for (int r = 0; r < 4; ++r)
          C[(long)(mb + r) * N + nn] = __float2bfloat16(v[r] + bb);
      } else if constexpr (MODE == 1) {
        __hip_bfloat16* C = (__hip_bfloat16*)Cv;
        long base = (long)(nn >> 11) * 2097152 + (nn & 2047);
#pragma unroll
        for (int r = 0; r < 4; ++r)
          C[(long)(mb + r) * 2048 + base] = __float2bfloat16(v[r] + bias[mb + r]);
      } else {
        float bb = bias[nn];
        float* C = (float*)Cv;
#pragma unroll
        for (int r = 0; r < 4; ++r)
          C[(long)(mb + r) * N + nn] = v[r] + bb;
      }
    }
  }
}

// ---------------- fused attention (R19 best: 2-tile ILP + raw v_exp_f32) --
// Final form. Verified-positive mechanisms: swapped QK^T (contiguous C rows),
// LDS-transposed nt P-stores (full 256B segments), XCD-affine bh-chunked
// remap (K/V cache-resident, FETCH 24MB), 2-tile-interleaved load/MFMA/exp
// chains, raw v_exp_f32, bf16-only staging with <<16 store expand.
// 10 further structural probes (TLP x3, order x3, cache x2, ILP split,
// cross-iter PV pipe) were null: kernel sits at a distributed latency
// floor, no pipe saturated.
__global__ __launch_bounds__(256) void attn_fwd(
    const short* __restrict__ Qb, const short* __restrict__ Kb,
    const short* __restrict__ VTb, float* __restrict__ attn_out,
    __hip_bfloat16* __restrict__ Wout)
{
  __shared__ short plds[4][32][152];  // per-wave: tile A cols [0,64), B at [72,136)
  const int S = 2048, D = 1024;
  const int bid = blockIdx.x;
  const int x = bid >> 7, r = bid & 127;
  const int bh = x * 8 + (r & 7), qi = r >> 3;
  const int b = bh >> 4, h = bh & 15;
  const int tid = threadIdx.x, w = tid >> 6, lane = tid & 63;
  const int g = lane >> 4, cc = lane & 15;
  const int q0 = qi * 128 + w * 32;

  const short* Qp = Qb + (long)b * S * D + h * 64;
  const short* Kp = Kb + (long)b * S * D + h * 64;
  const short* Vt = VTb + (long)bh * 64 * S;

  short8 qf[2][2];
#pragma unroll
  for (int mi = 0; mi < 2; ++mi)
#pragma unroll
    for (int ks = 0; ks < 2; ++ks)
      qf[mi][ks] = *(const short8*)(Qp + (long)(q0 + mi * 16 + cc) * D + ks * 32 + g * 8);

  float l[2] = {0.f, 0.f};
  const float C2 = 0.18033688011112042f;  // 0.125 * log2(e)

  // ---- pass 1: denominators, 2 tiles/iter ----
#pragma unroll 1
  for (int kt = 0; kt < S; kt += 128) {
    short8 kfA[2][4], kfB[2][4];
#pragma unroll
    for (int ks = 0; ks < 2; ++ks)
#pragma unroll
      for (int ni = 0; ni < 4; ++ni) {
        kfA[ks][ni] = *(const short8*)(Kp + (long)(kt + ni * 16 + cc) * D + ks * 32 + g * 8);
        kfB[ks][ni] = *(const short8*)(Kp + (long)(kt + 64 + ni * 16 + cc) * D + ks * 32 + g * 8);
      }
    float4v eA[2][4], eB[2][4];
#pragma unroll
    for (int mi = 0; mi < 2; ++mi)
#pragma unroll
      for (int ni = 0; ni < 4; ++ni) {
        eA[mi][ni] = (float4v){0.f, 0.f, 0.f, 0.f};
        eB[mi][ni] = (float4v){0.f, 0.f, 0.f, 0.f};
      }
#pragma unroll
    for (int ks = 0; ks < 2; ++ks)
#pragma unroll
      for (int mi = 0; mi < 2; ++mi)
#pragma unroll
        for (int ni = 0; ni < 4; ++ni) {
          eA[mi][ni] = __builtin_amdgcn_mfma_f32_16x16x32_bf16(
              kfA[ks][ni], qf[mi][ks], eA[mi][ni], 0, 0, 0);
          eB[mi][ni] = __builtin_amdgcn_mfma_f32_16x16x32_bf16(
              kfB[ks][ni], qf[mi][ks], eB[mi][ni], 0, 0, 0);
        }
#pragma unroll
    for (int mi = 0; mi < 2; ++mi)
#pragma unroll
      for (int ni = 0; ni < 4; ++ni)
#pragma unroll
        for (int r2 = 0; r2 < 4; ++r2) {
          l[mi] += fexp2(eA[mi][ni][r2] * C2);
          l[mi] += fexp2(eB[mi][ni][r2] * C2);
        }
  }
  float lrl[2];
#pragma unroll
  for (int mi = 0; mi < 2; ++mi) {
    float s = l[mi];
    s += __shfl_xor(s, 16);
    s += __shfl_xor(s, 32);
    lrl[mi] = -__log2f(s);
  }

  // ---- pass 2: 2 tiles/iter; P bf16 -> LDS; fp32 store; W = P @ V ----
  float4v Wacc[2][4];
#pragma unroll
  for (int mi = 0; mi < 2; ++mi)
#pragma unroll
    for (int ni = 0; ni < 4; ++ni) Wacc[mi][ni] = (float4v){0.f, 0.f, 0.f, 0.f};

  float* Arow = attn_out + (long)bh * S * S;
#pragma unroll 1
  for (int kt = 0; kt < S; kt += 128) {
    short8 kfA[2][4], kfB[2][4];
#pragma unroll
    for (int ks = 0; ks < 2; ++ks)
#pragma unroll
      for (int ni = 0; ni < 4; ++ni) {
        kfA[ks][ni] = *(const short8*)(Kp + (long)(kt + ni * 16 + cc) * D + ks * 32 + g * 8);
        kfB[ks][ni] = *(const short8*)(Kp + (long)(kt + 64 + ni * 16 + cc) * D + ks * 32 + g * 8);
      }
    float4v eA[2][4], eB[2][4];
#pragma unroll
    for (int mi = 0; mi < 2; ++mi)
#pragma unroll
      for (int ni = 0; ni < 4; ++ni) {
        eA[mi][ni] = (float4v){0.f, 0.f, 0.f, 0.f};
        eB[mi][ni] = (float4v){0.f, 0.f, 0.f, 0.f};
      }
#pragma unroll
    for (int ks = 0; ks < 2; ++ks)
#pragma unroll
      for (int mi = 0; mi < 2; ++mi)
#pragma unroll
        for (int ni = 0; ni < 4; ++ni) {
          eA[mi][ni] = __builtin_amdgcn_mfma_f32_16x16x32_bf16(
              kfA[ks][ni], qf[mi][ks], eA[mi][ni], 0, 0, 0);
          eB[mi][ni] = __builtin_amdgcn_mfma_f32_16x16x32_bf16(
              kfB[ks][ni], qf[mi][ks], eB[mi][ni], 0, 0, 0);
        }
    // softmax finish -> bf16 P tiles (A at col 0, B at col 72)
#pragma unroll
    for (int mi = 0; mi < 2; ++mi) {
#pragma unroll
      for (int ni = 0; ni < 4; ++ni) {
        short4v pbA, pbB;
#pragma unroll
        for (int r2 = 0; r2 < 4; ++r2) {
          pbA[r2] = f2bf(fexp2(__builtin_fmaf(eA[mi][ni][r2], C2, lrl[mi])));
          pbB[r2] = f2bf(fexp2(__builtin_fmaf(eB[mi][ni][r2], C2, lrl[mi])));
        }
        *(short4v*)&plds[w][mi * 16 + cc][ni * 16 + g * 4] = pbA;
        *(short4v*)&plds[w][mi * 16 + cc][72 + ni * 16 + g * 4] = pbB;
      }
    }
    // contiguous P stores from bf16 tiles (exact <<16 expand)
#pragma unroll
    for (int j = 0; j < 8; ++j) {
      uint2v uA = *(const uint2v*)&plds[w][j * 4 + g][cc * 4];
      uint2v uB = *(const uint2v*)&plds[w][j * 4 + g][72 + cc * 4];
      float4v pA, pB;
      pA[0] = __builtin_bit_cast(float, uA[0] << 16);
      pA[1] = __builtin_bit_cast(float, uA[0] & 0xffff0000u);
      pA[2] = __builtin_bit_cast(float, uA[1] << 16);
      pA[3] = __builtin_bit_cast(float, uA[1] & 0xffff0000u);
      pB[0] = __builtin_bit_cast(float, uB[0] << 16);
      pB[1] = __builtin_bit_cast(float, uB[0] & 0xffff0000u);
      pB[2] = __builtin_bit_cast(float, uB[1] << 16);
      pB[3] = __builtin_bit_cast(float, uB[1] & 0xffff0000u);
      float* rowp = Arow + (long)(q0 + j * 4 + g) * S + cc * 4;
      __builtin_nontemporal_store(pA, (float4v*)(rowp + kt));
      __builtin_nontemporal_store(pB, (float4v*)(rowp + kt + 64));
    }
    // PV accumulate, both tiles
#pragma unroll
    for (int ks = 0; ks < 2; ++ks) {
      short8 paA[2], paB[2], vfA[4], vfB[4];
#pragma unroll
      for (int mi = 0; mi < 2; ++mi) {
        paA[mi] = *(const short8*)&plds[w][mi * 16 + cc][ks * 32 + g * 8];
        paB[mi] = *(const short8*)&plds[w][mi * 16 + cc][72 + ks * 32 + g * 8];
      }
#pragma unroll
      for (int ni = 0; ni < 4; ++ni) {
        vfA[ni] = *(const short8*)(Vt + (long)(ni * 16 + cc) * S + kt + ks * 32 + g * 8);
        vfB[ni] = *(const short8*)(Vt + (long)(ni * 16 + cc) * S + kt + 64 + ks * 32 + g * 8);
      }
#pragma unroll
      for (int mi = 0; mi < 2; ++mi)
#pragma unroll
        for (int ni = 0; ni < 4; ++ni) {
          Wacc[mi][ni] = __builtin_amdgcn_mfma_f32_16x16x32_bf16(
              paA[mi], vfA[ni], Wacc[mi][ni], 0, 0, 0);
          Wacc[mi][ni] = __builtin_amdgcn_mfma_f32_16x16x32_bf16(
              paB[mi], vfB[ni], Wacc[mi][ni], 0, 0, 0);
        }
    }
  }

#pragma unroll
  for (int mi = 0; mi < 2; ++mi)
#pragma unroll
    for (int ni = 0; ni < 4; ++ni)
#pragma unroll
      for (int r2 = 0; r2 < 4; ++r2)
        Wout[(long)(b * S + q0 + mi * 16 + g * 4 + r2) * D + h * 64 + ni * 16 + cc] =
            __float2bfloat16(Wacc[mi][ni][r2]);
}

extern "C" void kernel_launch(void* const* d_in, const int* in_sizes, int n_in,
                              void* d_out, int out_size, void* d_ws, size_t ws_size,
                              hipStream_t stream) {
  const float* query = (const float*)d_in[0];
  const float* key   = (const float*)d_in[1];
  const float* value = (const float*)d_in[2];
  const float* wq_w  = (const float*)d_in[3];
  const float* wq_b  = (const float*)d_in[4];
  const float* wk_w  = (const float*)d_in[5];
  const float* wk_b  = (const float*)d_in[6];
  const float* wv_w  = (const float*)d_in[7];
  const float* wv_b  = (const float*)d_in[8];
  const float* fc_w  = (const float*)d_in[9];
  const float* fc_b  = (const float*)d_in[10];

  char* ws = (char*)d_ws;
  short* Qb  = (short*)(ws);                   // 16 MB  [B,S,D] bf16
  short* Kb  = (short*)(ws + 16777216);        // 16 MB
  short* VT  = (short*)(ws + 33554432);        // 16 MB  [B,H,64,S] bf16
  short* Wq  = (short*)(ws + 50331648);        // 2 MB each
  short* Wk  = (short*)(ws + 52428800);
  short* Wv  = (short*)(ws + 54525952);
  short* Wfc = (short*)(ws + 56623104);
  short* Xq  = (short*)(ws + 58720256);        // 16 MB each
  short* Xk  = (short*)(ws + 75497472);
  short* Xv  = (short*)(ws + 92274688);
  short* Wgt = Xq;  // weighted reuses Xq after projections

  float* out0 = (float*)d_out;                 // [B,S,D] fp32
  float* attn_out = out0 + 8388608;            // [B,H,S,S] fp32

  // casts (2 launches)
  cast3<<<dim3(8192, 3), 256, 0, stream>>>(
      (const float4v*)query, (const float4v*)key, (const float4v*)value,
      (short4v*)Xq, (short4v*)Xk, (short4v*)Xv, 2097152);
  cast4<<<dim3(1024, 4), 256, 0, stream>>>(
      (const float4v*)wq_w, (const float4v*)wk_w, (const float4v*)wv_w,
      (const float4v*)fc_w,
      (short4v*)Wq, (short4v*)Wk, (short4v*)Wv, (short4v*)Wfc, 262144);

  // Q and K projections merged into one dispatch (blockIdx.z selects)
  gemm_bt<0><<<dim3(64, 8, 2), 256, 0, stream>>>(
      Xq, Wq, wq_b, Qb, Xk, Wk, wk_b, Kb, 8192, 1024, 1024);
  // V projection with swapped operands -> writes V^T layout
  gemm_bt<1><<<dim3(8, 64), 256, 0, stream>>>(
      Wv, Xv, wv_b, VT, Wv, Xv, wv_b, VT, 1024, 8192, 1024);

  // attention (writes attention fp32 + weighted bf16)
  attn_fwd<<<dim3(1024), 256, 0, stream>>>(Qb, Kb, VT, attn_out,
                                           (__hip_bfloat16*)Wgt);

  // output projection
  gemm_bt<2><<<dim3(64, 8), 256, 0, stream>>>(
      Wgt, Wfc, fc_b, out0, Wgt, Wfc, fc_b, out0, 8192, 1024, 1024);
}